// Round 5
// baseline (311.316 us; speedup 1.0000x reference)
//
#include <hip/hip_runtime.h>
#include <hip/hip_bf16.h>

typedef __bf16 bf16x8 __attribute__((ext_vector_type(8)));
typedef float  f32x4  __attribute__((ext_vector_type(4)));

#define C_DIM   200
#define HW_DIM  1024
#define NT      13          // 13 row/col tiles of 16 (padded 208)
#define PADC    208
#define BK      64          // k-chunk staged per iteration
#define NKC     16          // 1024 / 64
#define ROWB    128         // bytes per LDS row (64 bf16)
#define TILEB   (PADC*ROWB) // 26624 B per buffer

__device__ __forceinline__ bf16x8 pack8(float4 a, float4 b){
  bf16x8 v;
  v[0]=(__bf16)a.x; v[1]=(__bf16)a.y; v[2]=(__bf16)a.z; v[3]=(__bf16)a.w;
  v[4]=(__bf16)b.x; v[5]=(__bf16)b.y; v[6]=(__bf16)b.z; v[7]=(__bf16)b.w;
  return v;
}

__global__ __launch_bounds__(832, 4)
void spectral_corr_kernel(const float* __restrict__ x,
                          const float* __restrict__ temp,
                          float* __restrict__ out)
{
  __shared__ __align__(16) char sA[2][TILEB];
  __shared__ float d_lds[PADC];
  __shared__ float rs_lds[PADC];

  const int tid = threadIdx.x;
  const int b   = blockIdx.x;
  const int w   = tid >> 6;   // wave id 0..12 -> row tile
  const int l   = tid & 63;
  const int g   = l >> 4;     // 0..3
  const int c   = l & 15;     // 0..15

  const float* xb = x + (size_t)b * (C_DIM * HW_DIM);

  // ---- staging slot assignment: 208 rows x 8 chunks of 8 floats = 1664 slots,
  //      832 threads -> 2 slots each. Swizzle: 16B-slot index ^= (row&7).
  const int s0 = tid,        s1 = tid + 832;
  const int r0 = s0 >> 3,    ch0 = s0 & 7;
  const int r1 = s1 >> 3,    ch1 = s1 & 7;
  const int wo0 = r0*ROWB + ((ch0*16) ^ ((r0&7)<<4));
  const int wo1 = r1*ROWB + ((ch1*16) ^ ((r1&7)<<4));
  const bool v1 = (r1 < C_DIM);   // rows 200..207 are zero padding

  f32x4 acc[NT];
  #pragma unroll
  for (int j=0;j<NT;++j) acc[j] = (f32x4){0.f,0.f,0.f,0.f};

  // ---- prologue: stage k-chunk 0 into buffer 0
  {
    const float* p0 = xb + r0*HW_DIM + ch0*8;
    float4 a0 = *(const float4*)p0;
    float4 a1 = *(const float4*)(p0+4);
    float4 b0 = make_float4(0.f,0.f,0.f,0.f), b1 = b0;
    if (v1){
      const float* p1 = xb + r1*HW_DIM + ch1*8;
      b0 = *(const float4*)p1; b1 = *(const float4*)(p1+4);
    }
    *reinterpret_cast<bf16x8*>(&sA[0][wo0]) = pack8(a0,a1);
    *reinterpret_cast<bf16x8*>(&sA[0][wo1]) = pack8(b0,b1);
  }
  __syncthreads();

  const float et = expf(temp[0]);   // hoisted; hides load+exp latency

  const int wrow = w*16 + c;        // this wave's A-frag row
  const int wro  = wrow*ROWB;
  const int wsw  = (wrow&7)<<4;

  // ---- main K loop, double-buffered, T14 issue-early/write-late
  for (int kc = 0; kc < NKC; ++kc){
    const char* base = sA[kc & 1];
    float4 a0,a1,b0,b1;
    const bool pre = (kc+1 < NKC);
    if (pre){
      const float* p0 = xb + r0*HW_DIM + (kc+1)*BK + ch0*8;
      a0 = *(const float4*)p0; a1 = *(const float4*)(p0+4);
      if (v1){
        const float* p1 = xb + r1*HW_DIM + (kc+1)*BK + ch1*8;
        b0 = *(const float4*)p1; b1 = *(const float4*)(p1+4);
      } else { b0 = make_float4(0.f,0.f,0.f,0.f); b1 = b0; }
    }
    #pragma unroll
    for (int s = 0; s < 2; ++s){          // two k-steps of 32
      const int kb = s*64 + g*16;         // byte offset of this lane's 8 k-elems
      bf16x8 fw = *reinterpret_cast<const bf16x8*>(base + wro + (kb ^ wsw));
      #pragma unroll
      for (int j = 0; j < NT; ++j){
        const int row = j*16 + c;
        bf16x8 fj = *reinterpret_cast<const bf16x8*>(
                        base + row*ROWB + (kb ^ ((row&7)<<4)));
        acc[j] = __builtin_amdgcn_mfma_f32_16x16x32_bf16(fw, fj, acc[j], 0, 0, 0);
      }
    }
    if (pre){
      char* dst = sA[(kc+1)&1];
      *reinterpret_cast<bf16x8*>(&dst[wo0]) = pack8(a0,a1);
      *reinterpret_cast<bf16x8*>(&dst[wo1]) = pack8(b0,b1);
    }
    __syncthreads();
  }

  // ---- diagonal of (bf16) G -> d_lds  (makes dcov_ii exactly 0)
  // C/D layout: col = lane&15, row-in-tile = 4*(lane>>4) + i
  #pragma unroll
  for (int j=0;j<NT;++j){
    if (j == w){                      // static acc index (rule #20)
      #pragma unroll
      for (int i=0;i<4;++i)
        if (c == g*4 + i) d_lds[j*16 + c] = acc[j][i];
    }
  }
  __syncthreads();

  // ---- dcov + per-row partial sums (over valid cols < 200)
  float dr[4];
  #pragma unroll
  for (int i=0;i<4;++i) dr[i] = d_lds[w*16 + g*4 + i];
  float rsum[4] = {0.f,0.f,0.f,0.f};
  #pragma unroll
  for (int j=0;j<NT;++j){
    const float dc = d_lds[j*16 + c];
    const bool cv  = (j*16 + c) < C_DIM;
    #pragma unroll
    for (int i=0;i<4;++i){
      float v = dr[i] + dc - 2.0f*acc[j][i];
      v = fmaxf(v, 0.0f);
      v = sqrtf(fmaf(et, v, 1e-5f));
      acc[j][i] = v;
      if (cv) rsum[i] += v;
    }
  }
  // reduce across the 16 lanes holding one row (low 4 lane bits)
  #pragma unroll
  for (int m=1;m<16;m<<=1){
    #pragma unroll
    for (int i=0;i<4;++i) rsum[i] += __shfl_xor(rsum[i], m, 64);
  }
  if (c == 0){
    #pragma unroll
    for (int i=0;i<4;++i) rs_lds[w*16 + g*4 + i] = rsum[i];
  }
  __syncthreads();

  // ---- total sum (uniform LDS broadcast loop)
  float tot = 0.f;
  for (int r=0;r<C_DIM;++r) tot += rs_lds[r];
  const float inv  = 1.0f/(float)C_DIM;
  const float totm = tot*inv*inv;

  // ---- fused double-centering + store:  out = rm_r + rm_c - totm - dcov
  float* ob = out + b*(C_DIM*C_DIM);
  float rmr[4];
  #pragma unroll
  for (int i=0;i<4;++i) rmr[i] = rs_lds[w*16 + g*4 + i]*inv;
  #pragma unroll
  for (int j=0;j<NT;++j){
    const int col = j*16 + c;
    if (col < C_DIM){
      const float rmc = rs_lds[col]*inv;
      #pragma unroll
      for (int i=0;i<4;++i){
        const int row = w*16 + g*4 + i;
        if (row < C_DIM)
          ob[row*C_DIM + col] = rmr[i] + rmc - totm - acc[j][i];
      }
    }
  }
}

extern "C" void kernel_launch(void* const* d_in, const int* in_sizes, int n_in,
                              void* d_out, int out_size, void* d_ws, size_t ws_size,
                              hipStream_t stream) {
  const float* x    = (const float*)d_in[0];
  const float* temp = (const float*)d_in[1];
  float* out        = (float*)d_out;
  spectral_corr_kernel<<<dim3(256), dim3(832), 0, stream>>>(x, temp, out);
}